// Round 1
// baseline (249.580 us; speedup 1.0000x reference)
//
#include <hip/hip_runtime.h>

#define TS   16    // spatial tile (output pixels per block side)
#define HALO 4
#define SW   24    // second tile width = TS + 2*HALO
#define CH   4     // channels per LDS chunk
#define C_   256
#define H_   128
#define W_   128
#define ND   9
#define NDISP 81

__global__ __launch_bounds__(256, 1) void corr_kernel(
    const float* __restrict__ first, const float* __restrict__ second,
    float* __restrict__ out)
{
    __shared__ float sF[CH][TS * TS];   // 4 KB
    __shared__ float sS[CH][SW * SW];   // 9.2 KB

    const int tid = threadIdx.x;      // 0..255
    const int bx  = blockIdx.x;       // 0..7
    const int by  = blockIdx.y;       // 0..7
    const int b   = blockIdx.z;       // 0..3

    const int tx = tid & 15;
    const int ty = tid >> 4;

    const int x0 = bx * TS;
    const int y0 = by * TS;

    float acc[NDISP];
    #pragma unroll
    for (int i = 0; i < NDISP; ++i) acc[i] = 0.f;

    const size_t plane = (size_t)H_ * W_;      // 16384
    const float* firstB  = first  + (size_t)b * C_ * plane;
    const float* secondB = second + (size_t)b * C_ * plane;

    // first-tile load mapping: thread t -> channel t/64, float4 slot (t%64)
    const int f_cc  = tid >> 6;          // 0..3
    const int f_idx = (tid & 63) * 4;    // 0..252
    const int f_y   = f_idx >> 4;
    const int f_x   = f_idx & 15;

    for (int c0 = 0; c0 < C_; c0 += CH) {
        __syncthreads();
        // stage first: CH channels x 256 floats, one float4 per thread
        {
            const float* src = firstB + (size_t)(c0 + f_cc) * plane
                             + (size_t)(y0 + f_y) * W_ + (x0 + f_x);
            float4 v = *reinterpret_cast<const float4*>(src);
            *reinterpret_cast<float4*>(&sF[f_cc][f_idx]) = v;
        }
        // stage second: CH channels x 24 rows x 6 float4 = 576 slots
        for (int s = tid; s < CH * SW * (SW / 4); s += 256) {
            const int cc  = s / (SW * (SW / 4));
            const int rem = s % (SW * (SW / 4));
            const int r   = rem / (SW / 4);
            const int q   = rem % (SW / 4);
            const int gy  = y0 - HALO + r;
            const int gx  = x0 - HALO + q * 4;   // always 0 mod 4
            float4 v = make_float4(0.f, 0.f, 0.f, 0.f);
            if ((unsigned)gy < (unsigned)H_ && (unsigned)gx < (unsigned)W_) {
                v = *reinterpret_cast<const float4*>(
                        secondB + (size_t)(c0 + cc) * plane + (size_t)gy * W_ + gx);
            }
            *reinterpret_cast<float4*>(&sS[cc][r * SW + q * 4]) = v;
        }
        __syncthreads();

        #pragma unroll
        for (int cc = 0; cc < CH; ++cc) {
            const float f = sF[cc][ty * TS + tx];
            #pragma unroll
            for (int dy = 0; dy < ND; ++dy) {
                const float* row = &sS[cc][(ty + dy) * SW + tx];
                #pragma unroll
                for (int dx = 0; dx < ND; ++dx) {
                    acc[dy * ND + dx] += f * row[dx];
                }
            }
        }
    }

    const float scale = 1.0f / C_;
    float* outB = out + (size_t)b * NDISP * plane
                + (size_t)(y0 + ty) * W_ + (x0 + tx);
    #pragma unroll
    for (int d = 0; d < NDISP; ++d) {
        outB[(size_t)d * plane] = acc[d] * scale;
    }
}

extern "C" void kernel_launch(void* const* d_in, const int* in_sizes, int n_in,
                              void* d_out, int out_size, void* d_ws, size_t ws_size,
                              hipStream_t stream) {
    const float* first  = (const float*)d_in[0];
    const float* second = (const float*)d_in[1];
    float* out = (float*)d_out;

    dim3 grid(W_ / TS, H_ / TS, 4);
    dim3 block(256);
    corr_kernel<<<grid, block, 0, stream>>>(first, second, out);
}

// Round 2
// 125.733 us; speedup vs baseline: 1.9850x; 1.9850x over previous
//
#include <hip/hip_runtime.h>

#define H_    128
#define W_    128
#define C_    256
#define ND    9
#define NDISP 81
#define TILE  8      // 8x8 query tile per block
#define HALO  4
#define NKEY  256    // 16x16 halo keys
#define KC    32     // channels per K-step
#define QROW  40     // ushorts per sQ row (32 ch + 8 pad) = 80 B
#define KROW  40     // ushorts per sK row = 80 B
#define SROW  258    // floats per sS row (256 + 2 pad)

typedef __attribute__((ext_vector_type(8))) short short8;
typedef __attribute__((ext_vector_type(4))) float f32x4;

__device__ __forceinline__ ushort f2bf(float x) {
    union { float f; unsigned u; } v; v.f = x;
    return (ushort)((v.u + 0x7fffu + ((v.u >> 16) & 1u)) >> 16);  // RNE
}

__global__ __launch_bounds__(256) void corr_mfma(
    const float* __restrict__ first, const float* __restrict__ second,
    float* __restrict__ out)
{
    __shared__ ushort sQ[64 * QROW];     //  5 KB
    __shared__ ushort sK[NKEY * KROW];   // 20 KB
    __shared__ float  sS[16 * SROW];     // 16.5 KB

    const int tid  = threadIdx.x;
    const int lane = tid & 63;
    const int wv   = tid >> 6;
    const int x0 = blockIdx.x * TILE;
    const int y0 = blockIdx.y * TILE;
    const int b  = blockIdx.z;

    const size_t plane = (size_t)H_ * W_;
    const float* fB  = first  + (size_t)b * C_ * plane;
    const float* sBp = second + (size_t)b * C_ * plane;

    // Q-stage mapping: thread -> (query q, 8-channel group wv)
    const int q  = tid & 63;
    const int qy = q >> 3, qx = q & 7;
    const float* qsrc = fB + (size_t)(y0 + qy) * W_ + (x0 + qx);

    // K-stage mapping: thread tid -> key pixel tid (16x16 halo), 32 channels
    const int ky = tid >> 4, kx = tid & 15;
    const int gy = y0 - HALO + ky, gx = x0 - HALO + kx;
    const bool kvalid = ((unsigned)gy < (unsigned)H_) && ((unsigned)gx < (unsigned)W_);
    const float* ksrc = sBp + (size_t)gy * W_ + gx;

    f32x4 acc[16];
    #pragma unroll
    for (int i = 0; i < 16; ++i) acc[i] = (f32x4){0.f, 0.f, 0.f, 0.f};

    // fragment byte offsets: A row = query 16*wv + (lane&15), k-group = lane>>4
    const int aOff  = (16 * wv + (lane & 15)) * (QROW * 2) + (lane >> 4) * 16;
    const int bBase = (lane & 15) * (KROW * 2) + (lane >> 4) * 16;

    for (int c0 = 0; c0 < C_; c0 += KC) {
        __syncthreads();
        // stage Q: 64 px x 32 ch bf16; one b128 write per thread
        {
            ushort tmp[8];
            #pragma unroll
            for (int j = 0; j < 8; ++j)
                tmp[j] = f2bf(qsrc[(size_t)(c0 + wv * 8 + j) * plane]);
            *reinterpret_cast<short8*>(&sQ[q * QROW + wv * 8]) =
                *reinterpret_cast<const short8*>(tmp);
        }
        // stage K halo: 256 px x 32 ch bf16; 4 b128 writes per thread
        #pragma unroll
        for (int cg = 0; cg < 4; ++cg) {
            ushort tmp[8];
            #pragma unroll
            for (int j = 0; j < 8; ++j) {
                float v = kvalid ? ksrc[(size_t)(c0 + cg * 8 + j) * plane] : 0.f;
                tmp[j] = f2bf(v);
            }
            *reinterpret_cast<short8*>(&sK[tid * KROW + cg * 8]) =
                *reinterpret_cast<const short8*>(tmp);
        }
        __syncthreads();

        const short8 a = *reinterpret_cast<const short8*>(
            reinterpret_cast<const char*>(sQ) + aOff);
        #pragma unroll
        for (int nt = 0; nt < 16; ++nt) {
            const short8 bf = *reinterpret_cast<const short8*>(
                reinterpret_cast<const char*>(sK) + bBase + nt * 16 * (KROW * 2));
            acc[nt] = __builtin_amdgcn_mfma_f32_16x16x32_bf16(a, bf, acc[nt], 0, 0, 0);
        }
    }

    // epilogue: 4 rounds, wave w dumps S[16 x 256] then all gather 81 disps/query
    const float scale = 1.0f / (float)C_;
    for (int w = 0; w < 4; ++w) {
        __syncthreads();
        if (wv == w) {
            #pragma unroll
            for (int nt = 0; nt < 16; ++nt) {
                const int col   = nt * 16 + (lane & 15);
                const int rbase = (lane >> 4) * 4;
                #pragma unroll
                for (int r = 0; r < 4; ++r)
                    sS[(rbase + r) * SROW + col] = acc[nt][r];
            }
        }
        __syncthreads();
        for (int idx = tid; idx < 16 * NDISP; idx += 256) {
            const int qi = idx & 15;
            const int d  = idx >> 4;
            const int dy = d / ND, dx = d % ND;
            const int gq  = w * 16 + qi;
            const int gqy = gq >> 3, gqx = gq & 7;
            const int key = (gqy + dy) * 16 + (gqx + dx);
            out[((size_t)b * NDISP + d) * plane + (size_t)(y0 + gqy) * W_ + (x0 + gqx)]
                = sS[qi * SROW + key] * scale;
        }
    }
}

extern "C" void kernel_launch(void* const* d_in, const int* in_sizes, int n_in,
                              void* d_out, int out_size, void* d_ws, size_t ws_size,
                              hipStream_t stream) {
    const float* first  = (const float*)d_in[0];
    const float* second = (const float*)d_in[1];
    float* out = (float*)d_out;

    dim3 grid(W_ / TILE, H_ / TILE, 4);
    dim3 block(256);
    corr_mfma<<<grid, block, 0, stream>>>(first, second, out);
}

// Round 3
// 65.142 us; speedup vs baseline: 3.8314x; 1.9301x over previous
//
#include <hip/hip_runtime.h>

#define H_    128
#define W_    128
#define C_    256
#define ND    9
#define NDISP 81
#define TILE  8      // 8x8 query tile per block
#define HALO  4
#define KC    32     // channels per K-step
#define QROW  40     // ushorts per sQ row (32 ch + 8 pad) = 80 B
#define KROW  40     // ushorts per sK row = 80 B
#define NT    10     // band: key rows 2w .. 2w+9 per wave
#define SROW  170    // floats per query in sS: 10 rows x 17

typedef __attribute__((ext_vector_type(8))) short short8;
typedef __attribute__((ext_vector_type(4))) float f32x4;

union SharedU {
    struct {
        ushort q[64 * QROW];    //  5120 B
        ushort k[256 * KROW];   // 20480 B
    } s;
    float sS[2][16 * SROW];     // 21760 B
};

__device__ __forceinline__ ushort f2bf(float x) {
    union { float f; unsigned u; } v; v.f = x;
    return (ushort)((v.u + 0x7fffu + ((v.u >> 16) & 1u)) >> 16);  // RNE
}

__global__ __launch_bounds__(256, 4) void corr_mfma(
    const float* __restrict__ first, const float* __restrict__ second,
    float* __restrict__ out)
{
    __shared__ SharedU sh;

    const int tid  = threadIdx.x;
    const int lane = tid & 63;
    const int wv   = tid >> 6;

    // XCD-aware swizzle: 128 consecutive tiles (half an image) per XCD
    const int bid  = blockIdx.x;                 // 0..1023
    const int tile = (bid & 7) * 128 + (bid >> 3);
    const int b  = tile >> 8;
    const int by = (tile >> 4) & 15;
    const int bx = tile & 15;
    const int x0 = bx * TILE;
    const int y0 = by * TILE;

    const size_t plane = (size_t)H_ * W_;
    const float* fB  = first  + (size_t)b * C_ * plane;
    const float* sBp = second + (size_t)b * C_ * plane;

    // Q-stage mapping: thread -> (query q = tid&63, 8-ch group wv)
    const int q  = tid & 63;
    const int qy = q >> 3, qx = q & 7;
    const float* qsrc = fB + (size_t)(y0 + qy) * W_ + (x0 + qx);

    // K-stage mapping: thread tid -> key pixel tid (16x16 halo), 32 channels
    const int ky = tid >> 4, kx = tid & 15;
    const int gy = y0 - HALO + ky, gx = x0 - HALO + kx;
    const bool kvalid = ((unsigned)gy < (unsigned)H_) && ((unsigned)gx < (unsigned)W_);
    const float* ksrc = sBp + (kvalid ? ((size_t)gy * W_ + gx) : 0);

    f32x4 acc[NT];
    #pragma unroll
    for (int i = 0; i < NT; ++i) acc[i] = (f32x4){0.f, 0.f, 0.f, 0.f};

    // fragment byte offsets
    const int aOff  = (16 * wv + (lane & 15)) * (QROW * 2) + (lane >> 4) * 16;
    const int bOff0 = ((2 * wv) * 16 + (lane & 15)) * (KROW * 2) + (lane >> 4) * 16;

    float qv[8], kv[32];
    // preload step 0
    #pragma unroll
    for (int j = 0; j < 8; ++j)  qv[j] = qsrc[(size_t)(wv * 8 + j) * plane];
    #pragma unroll
    for (int j = 0; j < 32; ++j) kv[j] = ksrc[(size_t)j * plane];

    for (int c0 = 0; c0 < C_; c0 += KC) {
        __syncthreads();   // previous step's fragment reads done
        // convert + write current step's staged registers to LDS
        {
            ushort tmp[8];
            #pragma unroll
            for (int j = 0; j < 8; ++j) tmp[j] = f2bf(qv[j]);
            *reinterpret_cast<short8*>(&sh.s.q[q * QROW + wv * 8]) =
                *reinterpret_cast<const short8*>(tmp);
        }
        #pragma unroll
        for (int cg = 0; cg < 4; ++cg) {
            ushort tmp[8];
            #pragma unroll
            for (int j = 0; j < 8; ++j)
                tmp[j] = f2bf(kvalid ? kv[cg * 8 + j] : 0.f);
            *reinterpret_cast<short8*>(&sh.s.k[tid * KROW + cg * 8]) =
                *reinterpret_cast<const short8*>(tmp);
        }
        // issue next step's loads (fire-and-forget over MFMA phase)
        if (c0 + KC < C_) {
            const int cn = c0 + KC;
            #pragma unroll
            for (int j = 0; j < 8; ++j)
                qv[j] = qsrc[(size_t)(cn + wv * 8 + j) * plane];
            #pragma unroll
            for (int j = 0; j < 32; ++j)
                kv[j] = ksrc[(size_t)(cn + j) * plane];
        }
        __syncthreads();   // LDS tiles ready

        const short8 a = *reinterpret_cast<const short8*>(
            reinterpret_cast<const char*>(sh.s.q) + aOff);
        #pragma unroll
        for (int nt = 0; nt < NT; ++nt) {
            const short8 bf = *reinterpret_cast<const short8*>(
                reinterpret_cast<const char*>(sh.s.k) + bOff0 + nt * 16 * (KROW * 2));
            acc[nt] = __builtin_amdgcn_mfma_f32_16x16x32_bf16(a, bf, acc[nt], 0, 0, 0);
        }
    }

    // epilogue: 2 rounds x 2 waves dump band-S, all threads gather
    const float scale = 1.0f / (float)C_;
    #pragma unroll
    for (int round = 0; round < 2; ++round) {
        __syncthreads();
        if ((wv >> 1) == round) {
            float* dst = sh.sS[wv & 1];
            #pragma unroll
            for (int nt = 0; nt < NT; ++nt) {
                #pragma unroll
                for (int r = 0; r < 4; ++r) {
                    const int qi = (lane >> 4) * 4 + r;
                    dst[qi * SROW + nt * 17 + (lane & 15)] = acc[nt][r];
                }
            }
        }
        __syncthreads();
        for (int idx = tid; idx < 2 * 16 * NDISP; idx += 256) {
            const int d  = idx >> 5;          // 0..80
            const int qq = idx & 31;          // 0..31
            const int p  = qq >> 4;           // wave within pair
            const int qi = qq & 15;
            const int dy = d / ND, dx = d % ND;
            const int wv2 = round * 2 + p;
            const int gqy = 2 * wv2 + (qi >> 3);
            const int gqx = qi & 7;
            const int lr  = (qi >> 3) + dy;
            const int col = gqx + dx;
            out[((size_t)b * NDISP + d) * plane + (size_t)(y0 + gqy) * W_ + (x0 + gqx)]
                = sh.sS[p][qi * SROW + lr * 17 + col] * scale;
        }
    }
}

extern "C" void kernel_launch(void* const* d_in, const int* in_sizes, int n_in,
                              void* d_out, int out_size, void* d_ws, size_t ws_size,
                              hipStream_t stream) {
    const float* first  = (const float*)d_in[0];
    const float* second = (const float*)d_in[1];
    float* out = (float*)d_out;

    dim3 grid(1024);
    dim3 block(256);
    corr_mfma<<<grid, block, 0, stream>>>(first, second, out);
}

// Round 4
// 54.708 us; speedup vs baseline: 4.5620x; 1.1907x over previous
//
#include <hip/hip_runtime.h>

#define H_    128
#define W_    128
#define C_    256
#define PLANE (H_*W_)
#define ND    9
#define NDISP 81
#define TILE  8
#define HALO  4
#define KC    32
#define NSTEP 8
#define NT    10     // band: key rows 2w .. 2w+9 per wave
#define SROW  170    // floats per query in sS: 10 rows x 17

typedef __attribute__((ext_vector_type(8))) short short8;
typedef __attribute__((ext_vector_type(4))) float f32x4;

union SharedU {
    float kbuf[2][8192];        // [buf][cg*1024 + px*4 + ch]  32 KB each, 64 KB total
    float sS[2][16 * SROW];     // epilogue scratch (21.8 KB, overlays kbuf[0])
};

__device__ __forceinline__ void gload_lds4(const float* g, float* l) {
    __builtin_amdgcn_global_load_lds(
        (const __attribute__((address_space(1))) void*)g,
        (__attribute__((address_space(3))) void*)l, 4, 0, 0);
}

__device__ __forceinline__ unsigned cvtpk(float lo, float hi) {
    unsigned r;
    asm("v_cvt_pk_bf16_f32 %0, %1, %2" : "=v"(r) : "v"(lo), "v"(hi));
    return r;
}

#define STAGE_Q(P, C0) do {                                                   \
    const unsigned long long qsb_ = (unsigned long long)(fB + (size_t)(C0) * PLANE); \
    _Pragma("unroll")                                                         \
    for (int j = 0; j < 8; ++j)                                               \
        asm volatile("global_load_dword %0, %1, %2"                           \
                     : "=v"(qf[P][j])                                         \
                     : "v"(vq + (unsigned)(j * PLANE * 4)), "s"(qsb_)         \
                     : "memory");                                             \
} while (0)

__global__ __launch_bounds__(256, 2) void corr_mfma(
    const float* __restrict__ first, const float* __restrict__ second,
    float* __restrict__ out)
{
    __shared__ SharedU sh;

    const int tid  = threadIdx.x;
    const int lane = tid & 63;
    const int wv   = tid >> 6;

    // XCD-aware swizzle: 128 consecutive tiles per XCD
    const int bid  = blockIdx.x;
    const int tile = (bid & 7) * 128 + (bid >> 3);
    const int b  = tile >> 8;
    const int by = (tile >> 4) & 15;
    const int bx = tile & 15;
    const int x0 = bx * TILE, y0 = by * TILE;

    const float* fB = first  + (size_t)b * C_ * PLANE;
    const float* sB = second + (size_t)b * C_ * PLANE;

    // ---- per-lane constants ----
    const int g   = lane >> 4;        // MFMA k-group
    const int kxq = lane & 15;        // B-frag key col / A-frag query idx
    // K staging mapping: lane = tq*4 + chl -> pixel tq, channel chl (of 4)
    const int chl = lane & 3;
    const int tq  = (lane >> 2) & 15;
    const int gxc = min(max(x0 - HALO + tq, 0), W_ - 1);
    const int koff = chl * PLANE + gxc;
    int rowoff[16];
    #pragma unroll
    for (int i = 0; i < 16; ++i)
        rowoff[i] = min(max(y0 - HALO + i, 0), H_ - 1) * W_;

    // Q direct-load: lane owns (query q, channels 8g..8g+7)
    const int q  = 16 * wv + kxq;
    const int qy = q >> 3, qx = q & 7;
    const unsigned vq = (unsigned)((g * 8 * PLANE + (y0 + qy) * W_ + (x0 + qx)) * 4);

    f32x4 acc[NT];
    #pragma unroll
    for (int i = 0; i < NT; ++i) acc[i] = (f32x4){0.f, 0.f, 0.f, 0.f};

    float qf[2][8];

    auto stageK = [&](int nb, int c0) {
        const float* kpA = sB + (size_t)(c0 + 8 * wv) * PLANE + koff;   // cg = 2w
        const float* kpB = kpA + 4 * PLANE;                             // cg = 2w+1
        float* ldA = &sh.kbuf[nb][(2 * wv) * 1024];
        float* ldB = ldA + 1024;
        #pragma unroll
        for (int i = 0; i < 16; ++i) {
            gload_lds4(kpA + rowoff[i], ldA + i * 64);
            gload_lds4(kpB + rowoff[i], ldB + i * 64);
        }
    };

    // ---- prologue: stage step 0 ----
    stageK(0, 0);
    STAGE_Q(0, 0);
    asm volatile("s_waitcnt vmcnt(0)" ::: "memory");
    __syncthreads();
    __builtin_amdgcn_sched_barrier(0);

    // ---- main loop: 8 K-steps, 2-phase pipeline ----
    #pragma unroll
    for (int s = 0; s < NSTEP; ++s) {
        const int p = s & 1;
        if (s < NSTEP - 1) {
            stageK(p ^ 1, (s + 1) * KC);
            if (p == 0) { STAGE_Q(1, (s + 1) * KC); } else { STAGE_Q(0, (s + 1) * KC); }
        }
        // A-fragment from prefetched registers
        unsigned a0, a1, a2, a3;
        if (p == 0) {
            a0 = cvtpk(qf[0][0], qf[0][1]); a1 = cvtpk(qf[0][2], qf[0][3]);
            a2 = cvtpk(qf[0][4], qf[0][5]); a3 = cvtpk(qf[0][6], qf[0][7]);
        } else {
            a0 = cvtpk(qf[1][0], qf[1][1]); a1 = cvtpk(qf[1][2], qf[1][3]);
            a2 = cvtpk(qf[1][4], qf[1][5]); a3 = cvtpk(qf[1][6], qf[1][7]);
        }
        union { unsigned u[4]; short8 v; } ua = {{a0, a1, a2, a3}};
        const float* krg = &sh.kbuf[p][0] + (2 * g) * 1024 + kxq * 4;
        #pragma unroll
        for (int nt = 0; nt < NT; ++nt) {
            const float* pp = krg + (2 * wv + nt) * 64;
            f32x4 f0 = *(const f32x4*)pp;
            f32x4 f1 = *(const f32x4*)(pp + 1024);
            unsigned b0 = cvtpk(f0[0], f0[1]);
            unsigned b1 = cvtpk(f0[2], f0[3]);
            unsigned b2 = cvtpk(f1[0], f1[1]);
            unsigned b3 = cvtpk(f1[2], f1[3]);
            union { unsigned u[4]; short8 v; } ub = {{b0, b1, b2, b3}};
            acc[nt] = __builtin_amdgcn_mfma_f32_16x16x32_bf16(ua.v, ub.v, acc[nt], 0, 0, 0);
        }
        asm volatile("s_waitcnt vmcnt(0)" ::: "memory");
        __syncthreads();
        __builtin_amdgcn_sched_barrier(0);
    }

    // ---- epilogue: 2 rounds x 2 waves dump band-S, all threads gather ----
    const float scale = 1.0f / (float)C_;
    #pragma unroll
    for (int round = 0; round < 2; ++round) {
        __syncthreads();
        if ((wv >> 1) == round) {
            float* dst = sh.sS[wv & 1];
            #pragma unroll
            for (int nt = 0; nt < NT; ++nt) {
                #pragma unroll
                for (int r = 0; r < 4; ++r) {
                    const int qi = (lane >> 4) * 4 + r;
                    dst[qi * SROW + nt * 17 + kxq] = acc[nt][r];
                }
            }
        }
        __syncthreads();
        for (int idx = tid; idx < 2 * 16 * NDISP; idx += 256) {
            const int d   = idx >> 5;
            const int qq  = idx & 31;
            const int pp2 = qq >> 4;
            const int qi  = qq & 15;
            const int dy = d / ND, dx = d % ND;
            const int wv2 = round * 2 + pp2;
            const int gqy = 2 * wv2 + (qi >> 3);
            const int gqx = qi & 7;
            const int lr  = (qi >> 3) + dy;
            const int col = gqx + dx;
            const int kyg = y0 + gqy - HALO + dy;
            const int kxg = x0 + gqx - HALO + dx;
            float v = 0.f;
            if ((unsigned)kyg < (unsigned)H_ && (unsigned)kxg < (unsigned)W_)
                v = sh.sS[pp2][qi * SROW + lr * 17 + col] * scale;
            out[((size_t)b * NDISP + d) * PLANE + (size_t)(y0 + gqy) * W_ + (x0 + gqx)] = v;
        }
    }
}

extern "C" void kernel_launch(void* const* d_in, const int* in_sizes, int n_in,
                              void* d_out, int out_size, void* d_ws, size_t ws_size,
                              hipStream_t stream) {
    const float* first  = (const float*)d_in[0];
    const float* second = (const float*)d_in[1];
    float* out = (float*)d_out;

    dim3 grid(1024);
    dim3 block(256);
    corr_mfma<<<grid, block, 0, stream>>>(first, second, out);
}